// Round 8
// baseline (3641.380 us; speedup 1.0000x reference)
//
#include <hip/hip_runtime.h>
#include <cmath>

#define TT 1024
#define BB 256
#define GG 16            // batch elements per block
#define NBLK (BB / GG)   // 16 blocks

typedef _Float16 f16x8 __attribute__((ext_vector_type(8)));
typedef float    f32x4 __attribute__((ext_vector_type(4)));
typedef _Float16 half2v __attribute__((ext_vector_type(2)));

__device__ __forceinline__ float fast_rcp(float x) { return __builtin_amdgcn_rcpf(x); }
__device__ __forceinline__ float fast_sigmoid(float x) { return fast_rcp(1.0f + __expf(-x)); }
__device__ __forceinline__ float fast_tanh(float x) {
    return 1.0f - 2.0f * fast_rcp(1.0f + __expf(2.0f * x));
}
__device__ __forceinline__ unsigned pack_f16(float a, float b) {
    half2v h; h.x = (_Float16)a; h.y = (_Float16)b;
    return __builtin_bit_cast(unsigned, h);
}
__device__ __forceinline__ float2 unpack_f16(unsigned u) {
    half2v h = __builtin_bit_cast(half2v, u);
    return make_float2((float)h.x, (float)h.y);
}
__device__ __forceinline__ void pin4(uint4& u) {
    asm volatile("" : "+v"(u.x), "+v"(u.y), "+v"(u.z), "+v"(u.w));
}
// LDS-ordered barrier that does NOT drain vmcnt: global stores (r2/r1u) stay
// in flight across steps. Safe: no global written in step m is read later by
// this kernel; LDS carries all cross-step state (lgkmcnt(0) orders it).
__device__ __forceinline__ void step_barrier() {
    asm volatile("s_waitcnt lgkmcnt(0)" ::: "memory");
    __builtin_amdgcn_s_barrier();
    __builtin_amdgcn_sched_barrier(0);
}

// ============================================================================
// One-time weight reorder into MFMA A-fragment order (fp16).
// Lane l holds rows (l&15), k = kt*32 + (l>>4)*8 + j, j=0..7. Tile (w,g) =
// gate g, hidden [16w,16w+16).
//   wfC : [8][4][6][64][8]  (L2: rows 512, K=192)
//   wfA0: [2][4][5][64][8]  (L0: rows 128, K=132 padded to 160, zero-padded)
//   wfA1: [4][4][3][64][8]  (L1: rows 256, K=96)
// ============================================================================
__global__ __launch_bounds__(256) void reorder_wf(
    const float* __restrict__ Wih0, const float* __restrict__ Whh0,
    const float* __restrict__ Wih1, const float* __restrict__ Whh1,
    const float* __restrict__ Wih2, const float* __restrict__ Whh2,
    _Float16* __restrict__ wfA0, _Float16* __restrict__ wfA1,
    _Float16* __restrict__ wfC)
{
    int idx = blockIdx.x * 256 + threadIdx.x;
    if (idx < 98304) {                       // C section
        int j = idx & 7, l = (idx >> 3) & 63, t = idx >> 9;  // t=(w*4+g)*6+kt
        int kt = t % 6, g = (t / 6) & 3, w = t / 24;
        int row = g * 128 + 16 * w + (l & 15);
        int k = kt * 32 + ((l >> 4) << 3) + j;
        float v = (k < 64) ? Wih2[row * 64 + k] : Whh2[row * 128 + (k - 64)];
        wfC[idx] = (_Float16)v;
    } else if (idx < 118784) {               // A0 section
        int f = idx - 98304;
        int j = f & 7, l = (f >> 3) & 63, t = f >> 9;        // t=(w*4+g)*5+kt
        int kt = t % 5, g = (t / 5) & 3, w = t / 20;
        int row = g * 32 + 16 * w + (l & 15);
        int k = kt * 32 + ((l >> 4) << 3) + j;
        float v = (k < 100) ? Wih0[row * 100 + k]
                : (k < 132) ? Whh0[row * 32 + (k - 100)] : 0.0f;
        wfA0[f] = (_Float16)v;
    } else if (idx < 143360) {               // A1 section
        int f = idx - 118784;
        int j = f & 7, l = (f >> 3) & 63, t = f >> 9;        // t=(w*4+g)*3+kt
        int kt = t % 3, g = (t / 3) & 3, w = t / 12;
        int row = g * 64 + 16 * w + (l & 15);
        int k = kt * 32 + ((l >> 4) << 3) + j;
        float v = (k < 32) ? Wih1[row * 32 + k] : Whh1[row * 64 + (k - 32)];
        wfA1[f] = (_Float16)v;
    }
}

// Fragment-linear LDS address helpers: element (col, k) of the B operand
// lives at frag[k>>5][((k&31)>>3)*16 + col] byte (k&7)*2.
#define FRAG_PTR(buf, k, col) ((char*)&(buf)[(k) >> 5][(((k) & 31) >> 3) * 16 + (col)] + ((k) & 7) * 2)

// ============================================================================
// Kernel A: fused LSTM layers 0+1 via MFMA. 16 blocks x 512 thr (8 waves):
// waves 0-1 = L0 GEMM (K=160, 5 kt), 2-5 = L1 GEMM lagged 1 step (K=96, 3 kt),
// 6-7 = x stagers. Fragment-linear double-buffered LDS; 1 barrier/step.
// ============================================================================
__global__ __attribute__((amdgpu_flat_work_group_size(512, 512),
                          amdgpu_waves_per_eu(1, 2)))
void lstm01_mfma(const float* __restrict__ x,       // [B, T, 100]
                 const _Float16* __restrict__ wfA0,
                 const _Float16* __restrict__ wfA1,
                 const float* __restrict__ b0_,     // [128]
                 const float* __restrict__ b1_,     // [256]
                 const float* __restrict__ h_0,     // [1, B, 32]
                 const float* __restrict__ c_0,     // [1, B, 32]
                 unsigned* __restrict__ r1u)        // [B, T, 32] uints (64 f16)
{
    const int b0b = blockIdx.x * GG;
    const int tid = threadIdx.x;
    const int w = tid >> 6, l = tid & 63;
    const int l15 = l & 15, lq = l >> 4;

    __shared__ alignas(16) uint4 X0F[2][5][64];   // K=160: x(0..100)|h0(100..132)|0pad
    __shared__ alignas(16) uint4 X1F[2][3][64];   // K=96:  h0(0..32)|h1(32..96)

    // --- role setup ---
    uint4 afu[20];
    unsigned bpk[8];
    float c[4] = {0.f, 0.f, 0.f, 0.f};
    int jb = 0;
    if (w < 2) {                               // L0: hidden jb..jb+3, 4 gates
        jb = 16 * w + 4 * lq;
        const uint4* wf4 = reinterpret_cast<const uint4*>(wfA0);
        #pragma unroll
        for (int g = 0; g < 4; ++g)
            #pragma unroll
            for (int kt = 0; kt < 5; ++kt) {
                afu[g * 5 + kt] = wf4[((w * 4 + g) * 5 + kt) * 64 + l];
                pin4(afu[g * 5 + kt]);
            }
        #pragma unroll
        for (int g = 0; g < 4; ++g)
            #pragma unroll
            for (int p = 0; p < 2; ++p)
                bpk[g * 2 + p] = pack_f16(b0_[g * 32 + jb + 2 * p],
                                          b0_[g * 32 + jb + 2 * p + 1]);
        #pragma unroll
        for (int r = 0; r < 4; ++r) c[r] = c_0[(b0b + l15) * 32 + jb + r];
    } else if (w < 6) {                        // L1
        const int w1 = w - 2;
        jb = 16 * w1 + 4 * lq;
        const uint4* wf4 = reinterpret_cast<const uint4*>(wfA1);
        #pragma unroll
        for (int g = 0; g < 4; ++g)
            #pragma unroll
            for (int kt = 0; kt < 3; ++kt) {
                afu[g * 3 + kt] = wf4[((w1 * 4 + g) * 3 + kt) * 64 + l];
                pin4(afu[g * 3 + kt]);
            }
        #pragma unroll
        for (int g = 0; g < 4; ++g)
            #pragma unroll
            for (int p = 0; p < 2; ++p)
                bpk[g * 2 + p] = pack_f16(b1_[g * 64 + jb + 2 * p],
                                          b1_[g * 64 + jb + 2 * p + 1]);
    }

    // --- init: x(0), h_0 into X0F[0]; zero pads (both bufs); zero X1F[1] h1 ---
    {
        #pragma unroll
        for (int e = 0; e < 2; ++e) {          // x(0): 800 f16-pairs
            int idx = tid + 512 * e;
            if (idx < 800) {
                int p = idx % 50, col = idx / 50;
                float2 xv = *reinterpret_cast<const float2*>(
                    &x[((size_t)(b0b + col) * TT) * 100 + 2 * p]);
                int k = 2 * p;
                *(unsigned*)FRAG_PTR(X0F[0], k, col) = pack_f16(xv.x, xv.y);
            }
        }
        {                                      // h_0: 16 cols x 32
            int col = tid >> 5, u = tid & 31, k = 100 + u;
            *(_Float16*)FRAG_PTR(X0F[0], k, col) = (_Float16)h_0[(b0b + col) * 32 + u];
        }
        if (tid < 448) {                       // K-pad [132,160): zero both bufs
            int col = tid / 28, u = tid % 28, k = 132 + u;
            *(_Float16*)FRAG_PTR(X0F[0], k, col) = (_Float16)0.f;
            *(_Float16*)FRAG_PTR(X0F[1], k, col) = (_Float16)0.f;
        }
        if (tid < 128)                         // X1F[1] h1-region (kt 1,2) = 0
            X1F[1][1 + (tid >> 6)][tid & 63] = (uint4){0, 0, 0, 0};
    }
    step_barrier();

    const int q = tid - 384;                   // stager index (w >= 6)

    for (int m = 0; m <= TT; ++m) {
        const int cur = m & 1, nxt = cur ^ 1;

        if (w < 2) {                                  // ---- L0: h0(m) ----
            if (m < TT) {
                f16x8 bf[5];
                #pragma unroll
                for (int kt = 0; kt < 5; ++kt)
                    bf[kt] = reinterpret_cast<const f16x8*>(&X0F[cur][kt][0])[l];
                f32x4 accA[4], accB[4];
                #pragma unroll
                for (int g = 0; g < 4; ++g) {
                    float2 u0 = unpack_f16(bpk[2 * g]);
                    float2 u1 = unpack_f16(bpk[2 * g + 1]);
                    accA[g] = (f32x4){u0.x, u0.y, u1.x, u1.y};
                    accB[g] = (f32x4){0.f, 0.f, 0.f, 0.f};
                }
                #pragma unroll
                for (int kt = 0; kt < 3; ++kt)
                    #pragma unroll
                    for (int g = 0; g < 4; ++g)
                        accA[g] = __builtin_amdgcn_mfma_f32_16x16x32_f16(
                            __builtin_bit_cast(f16x8, afu[g * 5 + kt]), bf[kt], accA[g], 0, 0, 0);
                #pragma unroll
                for (int kt = 3; kt < 5; ++kt)
                    #pragma unroll
                    for (int g = 0; g < 4; ++g)
                        accB[g] = __builtin_amdgcn_mfma_f32_16x16x32_f16(
                            __builtin_bit_cast(f16x8, afu[g * 5 + kt]), bf[kt], accB[g], 0, 0, 0);
                float h[4];
                #pragma unroll
                for (int r = 0; r < 4; ++r) {
                    float ai = fast_sigmoid(accA[0][r] + accB[0][r]);
                    float afg = fast_sigmoid(accA[1][r] + accB[1][r]);
                    float ag = fast_tanh(accA[2][r] + accB[2][r]);
                    float ao = fast_sigmoid(accA[3][r] + accB[3][r]);
                    c[r] = fmaf(afg, c[r], ai * ag);
                    h[r] = ao * fast_tanh(c[r]);
                }
                uint2 hp = make_uint2(pack_f16(h[0], h[1]), pack_f16(h[2], h[3]));
                *(uint2*)FRAG_PTR(X0F[nxt], 100 + jb, l15) = hp;   // L0's next h
                *(uint2*)FRAG_PTR(X1F[nxt], jb, l15) = hp;         // L1's next x
            }
        } else if (w < 6) {                           // ---- L1: h1(m-1) ----
            if (m >= 1) {
                f16x8 bf[3];
                #pragma unroll
                for (int kt = 0; kt < 3; ++kt)
                    bf[kt] = reinterpret_cast<const f16x8*>(&X1F[cur][kt][0])[l];
                f32x4 accA[4], accB[4];
                #pragma unroll
                for (int g = 0; g < 4; ++g) {
                    float2 u0 = unpack_f16(bpk[2 * g]);
                    float2 u1 = unpack_f16(bpk[2 * g + 1]);
                    accA[g] = (f32x4){u0.x, u0.y, u1.x, u1.y};
                    accB[g] = (f32x4){0.f, 0.f, 0.f, 0.f};
                }
                #pragma unroll
                for (int g = 0; g < 4; ++g) {
                    accA[g] = __builtin_amdgcn_mfma_f32_16x16x32_f16(
                        __builtin_bit_cast(f16x8, afu[g * 3 + 0]), bf[0], accA[g], 0, 0, 0);
                    accB[g] = __builtin_amdgcn_mfma_f32_16x16x32_f16(
                        __builtin_bit_cast(f16x8, afu[g * 3 + 1]), bf[1], accB[g], 0, 0, 0);
                    accA[g] = __builtin_amdgcn_mfma_f32_16x16x32_f16(
                        __builtin_bit_cast(f16x8, afu[g * 3 + 2]), bf[2], accA[g], 0, 0, 0);
                }
                float h[4];
                #pragma unroll
                for (int r = 0; r < 4; ++r) {
                    float ai = fast_sigmoid(accA[0][r] + accB[0][r]);
                    float afg = fast_sigmoid(accA[1][r] + accB[1][r]);
                    float ag = fast_tanh(accA[2][r] + accB[2][r]);
                    float ao = fast_sigmoid(accA[3][r] + accB[3][r]);
                    c[r] = fmaf(afg, c[r], ai * ag);
                    h[r] = ao * fast_tanh(c[r]);
                }
                uint2 hp = make_uint2(pack_f16(h[0], h[1]), pack_f16(h[2], h[3]));
                *(uint2*)FRAG_PTR(X1F[nxt], 32 + jb, l15) = hp;
                *reinterpret_cast<uint2*>(
                    r1u + (((size_t)(b0b + l15) * TT + (m - 1)) * 32 + (jb >> 1))) = hp;
            }
        } else {                                      // ---- stagers: x(m+1) ----
            if (m + 1 < TT) {
                #pragma unroll
                for (int e = 0; e < 7; ++e) {
                    int idx = q + 128 * e;
                    if (idx < 800) {
                        int p = idx % 50, col = idx / 50;
                        float2 xv = *reinterpret_cast<const float2*>(
                            &x[((size_t)(b0b + col) * TT + (m + 1)) * 100 + 2 * p]);
                        int k = 2 * p;
                        *(unsigned*)FRAG_PTR(X0F[nxt], k, col) = pack_f16(xv.x, xv.y);
                    }
                }
            }
        }
        step_barrier();   // cur consumed, nxt staged; stores stay in flight
    }
}

// ============================================================================
// Kernel C: LSTM layer 2 via MFMA. 16 blocks x 512 thr (8 waves), all GEMM.
// Wave w: gates i,f,g,o for hidden [16w,16w+16), K=192 (6 kt, split 3+3).
// Fragment-linear LDS; 1 custom barrier/step.
// ============================================================================
__global__ __attribute__((amdgpu_flat_work_group_size(512, 512),
                          amdgpu_waves_per_eu(1, 2)))
void lstm2_mfma(const unsigned* __restrict__ r1u,   // [B, T, 32] uints
                const _Float16* __restrict__ wfC,
                const float* __restrict__ b2,       // [512]
                float* __restrict__ r2)             // [B, T, 128]
{
    const int b0b = blockIdx.x * GG;
    const int tid = threadIdx.x;
    const int w = tid >> 6, l = tid & 63;
    const int l15 = l & 15, lq = l >> 4;
    const int jb = 16 * w + 4 * lq;

    uint4 af[24];
    {
        const uint4* wf4 = reinterpret_cast<const uint4*>(wfC);
        #pragma unroll
        for (int g = 0; g < 4; ++g)
            #pragma unroll
            for (int kt = 0; kt < 6; ++kt) {
                af[g * 6 + kt] = wf4[((w * 4 + g) * 6 + kt) * 64 + l];
                pin4(af[g * 6 + kt]);
            }
    }
    unsigned bpk[8];
    #pragma unroll
    for (int g = 0; g < 4; ++g)
        #pragma unroll
        for (int p = 0; p < 2; ++p)
            bpk[g * 2 + p] = pack_f16(b2[g * 128 + jb + 2 * p],
                                      b2[g * 128 + jb + 2 * p + 1]);

    __shared__ alignas(16) uint4 XB[2][6][64];   // K=192: r1(0..64)|h2(64..192)

    const int sc = tid >> 5, su = tid & 31;      // r1 stager mapping

    {   // init: r1(0) into XB[0] kt0-1; zero h2 region kt2-5
        unsigned v = r1u[((size_t)(b0b + sc) * TT) * 32 + su];
        *(unsigned*)FRAG_PTR(XB[0], 2 * su, sc) = v;
        if (tid < 256) XB[0][2 + (tid >> 6)][tid & 63] = (uint4){0, 0, 0, 0};
    }
    step_barrier();

    float c[4] = {0.f, 0.f, 0.f, 0.f};

    for (int m = 0; m < TT; ++m) {
        const int cur = m & 1, nxt = cur ^ 1;

        unsigned rn = 0;                              // prefetch r1(m+1)
        if (m + 1 < TT) rn = r1u[((size_t)(b0b + sc) * TT + (m + 1)) * 32 + su];

        f16x8 bf[6];
        #pragma unroll
        for (int kt = 0; kt < 6; ++kt)
            bf[kt] = reinterpret_cast<const f16x8*>(&XB[cur][kt][0])[l];

        f32x4 accA[4], accB[4];
        #pragma unroll
        for (int g = 0; g < 4; ++g) {
            float2 u0 = unpack_f16(bpk[2 * g]);
            float2 u1 = unpack_f16(bpk[2 * g + 1]);
            accA[g] = (f32x4){u0.x, u0.y, u1.x, u1.y};
            accB[g] = (f32x4){0.f, 0.f, 0.f, 0.f};
        }
        #pragma unroll
        for (int kt = 0; kt < 3; ++kt)
            #pragma unroll
            for (int g = 0; g < 4; ++g) {
                accA[g] = __builtin_amdgcn_mfma_f32_16x16x32_f16(
                    __builtin_bit_cast(f16x8, af[g * 6 + kt]), bf[kt], accA[g], 0, 0, 0);
                accB[g] = __builtin_amdgcn_mfma_f32_16x16x32_f16(
                    __builtin_bit_cast(f16x8, af[g * 6 + 3 + kt]), bf[3 + kt], accB[g], 0, 0, 0);
            }

        float h[4];
        #pragma unroll
        for (int r = 0; r < 4; ++r) {
            float ai = fast_sigmoid(accA[0][r] + accB[0][r]);
            float afg = fast_sigmoid(accA[1][r] + accB[1][r]);
            float ag = fast_tanh(accA[2][r] + accB[2][r]);
            float ao = fast_sigmoid(accA[3][r] + accB[3][r]);
            c[r] = fmaf(afg, c[r], ai * ag);
            h[r] = ao * fast_tanh(c[r]);
        }
        uint2 hp = make_uint2(pack_f16(h[0], h[1]), pack_f16(h[2], h[3]));
        *(uint2*)FRAG_PTR(XB[nxt], 64 + jb, l15) = hp;
        float4 hv = make_float4(h[0], h[1], h[2], h[3]);
        *reinterpret_cast<float4*>(
            r2 + ((size_t)(b0b + l15) * TT + m) * 128 + jb) = hv;
        if (m + 1 < TT)
            *(unsigned*)FRAG_PTR(XB[nxt], 2 * su, sc) = rn;
        step_barrier();
    }
}

// out[bt] = tanh(dot(r2[bt,:128], Wl) + bl)
__global__ __launch_bounds__(256) void final_proj(
    const float* __restrict__ r,   // [B*T, 128]
    const float* __restrict__ Wl,  // [128]
    const float* __restrict__ bl,  // [1]
    float* __restrict__ out)       // [B*T]
{
    __shared__ float wl[128];
    const int tid = threadIdx.x;
    if (tid < 128) wl[tid] = Wl[tid];
    __syncthreads();

    const int bt = blockIdx.x * 256 + tid;
    const float4* rr = reinterpret_cast<const float4*>(r + (size_t)bt * 128);
    float a0 = 0.f, a1 = 0.f, a2 = 0.f, a3 = 0.f;
    #pragma unroll
    for (int k = 0; k < 32; ++k) {
        float4 v = rr[k];
        a0 = fmaf(v.x, wl[4 * k + 0], a0);
        a1 = fmaf(v.y, wl[4 * k + 1], a1);
        a2 = fmaf(v.z, wl[4 * k + 2], a2);
        a3 = fmaf(v.w, wl[4 * k + 3], a3);
    }
    out[bt] = tanhf(((a0 + a1) + (a2 + a3)) + bl[0]);
}

extern "C" void kernel_launch(void* const* d_in, const int* in_sizes, int n_in,
                              void* d_out, int out_size, void* d_ws, size_t ws_size,
                              hipStream_t stream) {
    const float* input = (const float*)d_in[0];
    const float* h_0   = (const float*)d_in[1];
    const float* c_0   = (const float*)d_in[2];
    const float* Wih0  = (const float*)d_in[3];
    const float* Whh0  = (const float*)d_in[4];
    const float* b0    = (const float*)d_in[5];
    const float* Wih1  = (const float*)d_in[6];
    const float* Whh1  = (const float*)d_in[7];
    const float* b1    = (const float*)d_in[8];
    const float* Wih2  = (const float*)d_in[9];
    const float* Whh2  = (const float*)d_in[10];
    const float* b2    = (const float*)d_in[11];
    const float* Wl    = (const float*)d_in[12];
    const float* bl    = (const float*)d_in[13];

    float* out = (float*)d_out;                 // [B*T] head output
    float* r2  = out + (size_t)BB * TT;         // [B,T,128] second output

    char* ws = (char*)d_ws;
    unsigned*  r1u  = (unsigned*)ws;                       // 33,554,432 B
    _Float16*  wfC  = (_Float16*)(ws + 33554432);          //    196,608 B
    _Float16*  wfA0 = (_Float16*)(ws + 33751040);          //     40,960 B
    _Float16*  wfA1 = (_Float16*)(ws + 33792000);          //     49,152 B

    hipLaunchKernelGGL(reorder_wf, dim3(560), dim3(256), 0, stream,
                       Wih0, Whh0, Wih1, Whh1, Wih2, Whh2, wfA0, wfA1, wfC);
    hipLaunchKernelGGL(lstm01_mfma, dim3(NBLK), dim3(512), 0, stream,
                       input, wfA0, wfA1, b0, b1, h_0, c_0, r1u);
    hipLaunchKernelGGL(lstm2_mfma, dim3(NBLK), dim3(512), 0, stream,
                       r1u, wfC, b2, r2);
    hipLaunchKernelGGL(final_proj, dim3(BB * TT / 256), dim3(256), 0, stream,
                       r2, Wl, bl, out);
}

// Round 9
// 1858.181 us; speedup vs baseline: 1.9596x; 1.9596x over previous
//
#include <hip/hip_runtime.h>
#include <cmath>

#define TT 1024
#define BB 256
#define GG 16            // batch elements per block (MFMA N)
#define NBLK (BB / GG)   // 16 blocks

typedef _Float16 f16x8 __attribute__((ext_vector_type(8)));
typedef float    f32x4 __attribute__((ext_vector_type(4)));
typedef _Float16 half2v __attribute__((ext_vector_type(2)));

__device__ __forceinline__ float fast_rcp(float x) { return __builtin_amdgcn_rcpf(x); }
__device__ __forceinline__ float fast_sigmoid(float x) { return fast_rcp(1.0f + __expf(-x)); }
__device__ __forceinline__ float fast_tanh(float x) {
    return 1.0f - 2.0f * fast_rcp(1.0f + __expf(2.0f * x));
}
__device__ __forceinline__ unsigned pack_f16(float a, float b) {
    half2v h; h.x = (_Float16)a; h.y = (_Float16)b;
    return __builtin_bit_cast(unsigned, h);
}
__device__ __forceinline__ float2 unpack_f16(unsigned u) {
    half2v h = __builtin_bit_cast(half2v, u);
    return make_float2((float)h.x, (float)h.y);
}
__device__ __forceinline__ void pin4(uint4& u) {
    asm volatile("" : "+v"(u.x), "+v"(u.y), "+v"(u.z), "+v"(u.w));
}
// LDS-ordered barrier that does NOT drain vmcnt: global stores stay in
// flight across steps. Safe: no global written in step m is read later by
// the same kernel; LDS carries all cross-step state.
__device__ __forceinline__ void step_barrier() {
    asm volatile("s_waitcnt lgkmcnt(0)" ::: "memory");
    __builtin_amdgcn_s_barrier();
    __builtin_amdgcn_sched_barrier(0);
}

// Fragment addressing: element (k, col) of a B-frag tile set lives at
// buf[k>>5][((k&31)>>3)*16 + col], byte (k&7)*2. Lane l of the consuming
// wave reads uint4 index l of frag kt (k = kt*32 + (l>>4)*8 + j).
#define FRAG_PTR(buf, k, col) ((char*)&(buf)[(k) >> 5][(((k) & 31) >> 3) * 16 + (col)] + ((k) & 7) * 2)
#define GFRAG_PTR(base, k, col) ((char*)(base) + ((((k) >> 5) * 64 + (((k) & 31) >> 3) * 16 + (col)) * 16 + ((k) & 7) * 2))

// ============================================================================
// Weight reorder into MFMA A-fragment order (fp16). Lane l holds rows (l&15),
// k = kt*32 + (l>>4)*8 + j. Tile (w,g) = gate g, hidden [16w,16w+16).
//   wfC : [8][4][6][64][8]  L2 K-order [r1(64)|h2(128)]
//   wfA0: [2][4][5][64][8]  L0 K-order [h0(32)|x(100)|pad(28)=0]
//   wfA1: [4][4][3][64][8]  L1 K-order [h0(32)|h1(64)]
// ============================================================================
__global__ __launch_bounds__(256) void reorder_wf(
    const float* __restrict__ Wih0, const float* __restrict__ Whh0,
    const float* __restrict__ Wih1, const float* __restrict__ Whh1,
    const float* __restrict__ Wih2, const float* __restrict__ Whh2,
    _Float16* __restrict__ wfA0, _Float16* __restrict__ wfA1,
    _Float16* __restrict__ wfC)
{
    int idx = blockIdx.x * 256 + threadIdx.x;
    if (idx < 98304) {                       // C section
        int j = idx & 7, l = (idx >> 3) & 63, t = idx >> 9;
        int kt = t % 6, g = (t / 6) & 3, w = t / 24;
        int row = g * 128 + 16 * w + (l & 15);
        int k = kt * 32 + ((l >> 4) << 3) + j;
        float v = (k < 64) ? Wih2[row * 64 + k] : Whh2[row * 128 + (k - 64)];
        wfC[idx] = (_Float16)v;
    } else if (idx < 118784) {               // A0 section (new K-order!)
        int f = idx - 98304;
        int j = f & 7, l = (f >> 3) & 63, t = f >> 9;
        int kt = t % 5, g = (t / 5) & 3, w = t / 20;
        int row = g * 32 + 16 * w + (l & 15);
        int k = kt * 32 + ((l >> 4) << 3) + j;
        float v = (k < 32)  ? Whh0[row * 32 + k]
                : (k < 132) ? Wih0[row * 100 + (k - 32)] : 0.0f;
        wfA0[f] = (_Float16)v;
    } else if (idx < 143360) {               // A1 section
        int f = idx - 118784;
        int j = f & 7, l = (f >> 3) & 63, t = f >> 9;
        int kt = t % 3, g = (t / 3) & 3, w = t / 12;
        int row = g * 64 + 16 * w + (l & 15);
        int k = kt * 32 + ((l >> 4) << 3) + j;
        float v = (k < 32) ? Wih1[row * 32 + k] : Whh1[row * 64 + (k - 32)];
        wfA1[f] = (_Float16)v;
    }
}

// ============================================================================
// Pre-pack x into B-fragment order (one pass, bandwidth-bound).
//   xf123[blk][t][kt=0..2][l] uint4 : x[kt*32 + (l>>4)*8 + j], col = l&15
//   xf4c [blk][t][col] uint2        : x[96..100] packed (kt4 tail, lq==0)
// ============================================================================
__global__ __launch_bounds__(256) void pack_x(
    const float* __restrict__ x, uint4* __restrict__ xf123,
    uint2* __restrict__ xf4c)
{
    int idx = blockIdx.x * 256 + threadIdx.x;
    if (idx < 16 * 1024 * 3 * 64) {
        int l   = idx & 63;
        int kt  = (idx >> 6) % 3;
        int t   = ((idx >> 6) / 3) & 1023;
        int blk = (idx >> 6) / 3 / 1024;
        int col = l & 15, lq = l >> 4;
        int xidx = kt * 32 + lq * 8;
        const float* xr = x + ((size_t)(blk * GG + col) * TT + t) * 100 + xidx;
        float4 a = *reinterpret_cast<const float4*>(xr);
        float4 b = *reinterpret_cast<const float4*>(xr + 4);
        uint4 u;
        u.x = pack_f16(a.x, a.y); u.y = pack_f16(a.z, a.w);
        u.z = pack_f16(b.x, b.y); u.w = pack_f16(b.z, b.w);
        xf123[idx] = u;
    } else {
        int f = idx - 16 * 1024 * 3 * 64;     // exactly 16*1024*16 threads
        int col = f & 15;
        int t   = (f >> 4) & 1023;
        int blk = f >> 14;
        const float* xr = x + ((size_t)(blk * GG + col) * TT + t) * 100 + 96;
        float4 a = *reinterpret_cast<const float4*>(xr);
        uint2 u; u.x = pack_f16(a.x, a.y); u.y = pack_f16(a.z, a.w);
        xf4c[f] = u;
    }
}

// ============================================================================
// Kernel A: fused LSTM layers 0+1 via MFMA. 16 blocks x 384 thr (6 waves):
// waves 0-1 = L0 (K=160: kt0=h0 LDS, kt1-3=x global regs, kt4=x-tail global),
// waves 2-5 = L1 lagged 1 step (K=96: kt0=h0 LDS shared, kt1-2=h1 LDS).
// No staging waves; x prefetched 1 step ahead into registers. r1 written in
// fragment order for kernel C's direct-global B reads. 1 barrier/step.
// ============================================================================
__global__ __attribute__((amdgpu_flat_work_group_size(384, 384),
                          amdgpu_waves_per_eu(1, 2)))
void lstm01_mfma(const uint4* __restrict__ xf123,
                 const uint2* __restrict__ xf4c,
                 const _Float16* __restrict__ wfA0,
                 const _Float16* __restrict__ wfA1,
                 const float* __restrict__ b0_,     // [128]
                 const float* __restrict__ b1_,     // [256]
                 const float* __restrict__ h_0,     // [1, B, 32]
                 const float* __restrict__ c_0,     // [1, B, 32]
                 uint4* __restrict__ r1f)           // [16][1024][2][64]
{
    const int blk = blockIdx.x;
    const int b0b = blk * GG;
    const int tid = threadIdx.x;
    const int w = tid >> 6, l = tid & 63;
    const int l15 = l & 15, lq = l >> 4;

    __shared__ alignas(16) uint4 H0F[2][1][64];   // h0 frag (kt0 of L0 & L1)
    __shared__ alignas(16) uint4 H1F[2][2][64];   // h1 frags (kt1-2 of L1)

    // --- role setup ---
    uint4 afu[20];
    unsigned bpk[8];
    float c[4] = {0.f, 0.f, 0.f, 0.f};
    int jb = 0;
    if (w < 2) {                               // L0
        jb = 16 * w + 4 * lq;
        const uint4* wf4 = reinterpret_cast<const uint4*>(wfA0);
        #pragma unroll
        for (int g = 0; g < 4; ++g)
            #pragma unroll
            for (int kt = 0; kt < 5; ++kt) {
                afu[g * 5 + kt] = wf4[((w * 4 + g) * 5 + kt) * 64 + l];
                pin4(afu[g * 5 + kt]);
            }
        #pragma unroll
        for (int g = 0; g < 4; ++g)
            #pragma unroll
            for (int p = 0; p < 2; ++p)
                bpk[g * 2 + p] = pack_f16(b0_[g * 32 + jb + 2 * p],
                                          b0_[g * 32 + jb + 2 * p + 1]);
        #pragma unroll
        for (int r = 0; r < 4; ++r) c[r] = c_0[(b0b + l15) * 32 + jb + r];
    } else {                                   // L1
        const int w1 = w - 2;
        jb = 16 * w1 + 4 * lq;
        const uint4* wf4 = reinterpret_cast<const uint4*>(wfA1);
        #pragma unroll
        for (int g = 0; g < 4; ++g)
            #pragma unroll
            for (int kt = 0; kt < 3; ++kt) {
                afu[g * 3 + kt] = wf4[((w1 * 4 + g) * 3 + kt) * 64 + l];
                pin4(afu[g * 3 + kt]);
            }
        #pragma unroll
        for (int g = 0; g < 4; ++g)
            #pragma unroll
            for (int p = 0; p < 2; ++p)
                bpk[g * 2 + p] = pack_f16(b1_[g * 64 + jb + 2 * p],
                                          b1_[g * 64 + jb + 2 * p + 1]);
    }

    // --- init LDS: H0F[0] = h_0; H1F[1] = 0 (h1(-1)) ---
    #pragma unroll
    for (int e = 0; e < 2; ++e) {
        int idx = tid + 384 * e;
        if (idx < 512) {
            int col = idx >> 5, u = idx & 31;
            *(_Float16*)FRAG_PTR(H0F[0], u, col) =
                (_Float16)h_0[(b0b + col) * 32 + u];
        }
    }
    if (tid < 128) H1F[1][tid >> 6][tid & 63] = (uint4){0, 0, 0, 0};

    // --- L0 x prefetch (t=0) ---
    uint4 bx0 = {0,0,0,0}, bx1 = {0,0,0,0}, bx2 = {0,0,0,0};
    uint2 bx4 = {0, 0};
    if (w < 2) {
        size_t o = ((size_t)blk * TT) * 3 * 64 + l;
        bx0 = xf123[o]; bx1 = xf123[o + 64]; bx2 = xf123[o + 128];
        bx4 = xf4c[((size_t)blk * TT) * 16 + l15];
    }
    step_barrier();

    for (int m = 0; m <= TT; ++m) {
        const int cur = m & 1, nxt = cur ^ 1;

        if (w < 2) {                                  // ---- L0: h0(m) ----
            uint4 cx0 = bx0, cx1 = bx1, cx2 = bx2;
            uint2 cx4 = bx4;
            if (m + 1 < TT) {                         // prefetch x(m+1)
                size_t o = ((size_t)blk * TT + (m + 1)) * 3 * 64 + l;
                bx0 = xf123[o]; bx1 = xf123[o + 64]; bx2 = xf123[o + 128];
                bx4 = xf4c[((size_t)blk * TT + (m + 1)) * 16 + l15];
            }
            if (m < TT) {
                f16x8 bh = reinterpret_cast<const f16x8*>(&H0F[cur][0][0])[l];
                uint4 t4;
                t4.x = (lq == 0) ? cx4.x : 0u;
                t4.y = (lq == 0) ? cx4.y : 0u;
                t4.z = 0u; t4.w = 0u;
                f16x8 bf4 = __builtin_bit_cast(f16x8, t4);
                f16x8 b1v = __builtin_bit_cast(f16x8, cx0);
                f16x8 b2v = __builtin_bit_cast(f16x8, cx1);
                f16x8 b3v = __builtin_bit_cast(f16x8, cx2);

                f32x4 accA[4], accB[4];
                #pragma unroll
                for (int g = 0; g < 4; ++g) {
                    float2 u0 = unpack_f16(bpk[2 * g]);
                    float2 u1 = unpack_f16(bpk[2 * g + 1]);
                    accA[g] = (f32x4){u0.x, u0.y, u1.x, u1.y};
                    accB[g] = (f32x4){0.f, 0.f, 0.f, 0.f};
                }
                #pragma unroll
                for (int g = 0; g < 4; ++g) {
                    accA[g] = __builtin_amdgcn_mfma_f32_16x16x32_f16(
                        __builtin_bit_cast(f16x8, afu[g * 5 + 0]), bh, accA[g], 0, 0, 0);
                    accB[g] = __builtin_amdgcn_mfma_f32_16x16x32_f16(
                        __builtin_bit_cast(f16x8, afu[g * 5 + 1]), b1v, accB[g], 0, 0, 0);
                    accA[g] = __builtin_amdgcn_mfma_f32_16x16x32_f16(
                        __builtin_bit_cast(f16x8, afu[g * 5 + 2]), b2v, accA[g], 0, 0, 0);
                    accB[g] = __builtin_amdgcn_mfma_f32_16x16x32_f16(
                        __builtin_bit_cast(f16x8, afu[g * 5 + 3]), b3v, accB[g], 0, 0, 0);
                    accA[g] = __builtin_amdgcn_mfma_f32_16x16x32_f16(
                        __builtin_bit_cast(f16x8, afu[g * 5 + 4]), bf4, accA[g], 0, 0, 0);
                }
                float h[4];
                #pragma unroll
                for (int r = 0; r < 4; ++r) {
                    float ai  = fast_sigmoid(accA[0][r] + accB[0][r]);
                    float afg = fast_sigmoid(accA[1][r] + accB[1][r]);
                    float ag  = fast_tanh(accA[2][r] + accB[2][r]);
                    float ao  = fast_sigmoid(accA[3][r] + accB[3][r]);
                    c[r] = fmaf(afg, c[r], ai * ag);
                    h[r] = ao * fast_tanh(c[r]);
                }
                uint2 hp = make_uint2(pack_f16(h[0], h[1]), pack_f16(h[2], h[3]));
                *(uint2*)FRAG_PTR(H0F[nxt], jb, l15) = hp;   // next h0 frag
            }
        } else {                                      // ---- L1: h1(m-1) ----
            if (m >= 1) {
                f16x8 bh0 = reinterpret_cast<const f16x8*>(&H0F[cur][0][0])[l];
                f16x8 bh1 = reinterpret_cast<const f16x8*>(&H1F[cur][0][0])[l];
                f16x8 bh2 = reinterpret_cast<const f16x8*>(&H1F[cur][1][0])[l];

                f32x4 accA[4], accB[4];
                #pragma unroll
                for (int g = 0; g < 4; ++g) {
                    float2 u0 = unpack_f16(bpk[2 * g]);
                    float2 u1 = unpack_f16(bpk[2 * g + 1]);
                    accA[g] = (f32x4){u0.x, u0.y, u1.x, u1.y};
                    accB[g] = (f32x4){0.f, 0.f, 0.f, 0.f};
                }
                #pragma unroll
                for (int g = 0; g < 4; ++g) {
                    accA[g] = __builtin_amdgcn_mfma_f32_16x16x32_f16(
                        __builtin_bit_cast(f16x8, afu[g * 3 + 0]), bh0, accA[g], 0, 0, 0);
                    accB[g] = __builtin_amdgcn_mfma_f32_16x16x32_f16(
                        __builtin_bit_cast(f16x8, afu[g * 3 + 1]), bh1, accB[g], 0, 0, 0);
                    accA[g] = __builtin_amdgcn_mfma_f32_16x16x32_f16(
                        __builtin_bit_cast(f16x8, afu[g * 3 + 2]), bh2, accA[g], 0, 0, 0);
                }
                float h[4];
                #pragma unroll
                for (int r = 0; r < 4; ++r) {
                    float ai  = fast_sigmoid(accA[0][r] + accB[0][r]);
                    float afg = fast_sigmoid(accA[1][r] + accB[1][r]);
                    float ag  = fast_tanh(accA[2][r] + accB[2][r]);
                    float ao  = fast_sigmoid(accA[3][r] + accB[3][r]);
                    c[r] = fmaf(afg, c[r], ai * ag);
                    h[r] = ao * fast_tanh(c[r]);
                }
                uint2 hp = make_uint2(pack_f16(h[0], h[1]), pack_f16(h[2], h[3]));
                *(uint2*)FRAG_PTR(H1F[nxt], jb, l15) = hp;
                uint4* base = r1f + ((size_t)blk * TT + (m - 1)) * 128;
                *(uint2*)GFRAG_PTR(base, jb, l15) = hp;      // frag-order global
            }
        }
        step_barrier();
    }
}

// ============================================================================
// Kernel C: LSTM layer 2 via MFMA. 16 blocks x 512 thr (8 waves), all GEMM.
// K=192: kt0-1 = r1 direct from global (reg prefetch), kt2-5 = h2 LDS.
// ============================================================================
__global__ __attribute__((amdgpu_flat_work_group_size(512, 512),
                          amdgpu_waves_per_eu(1, 2)))
void lstm2_mfma(const uint4* __restrict__ r1f,      // [16][1024][2][64]
                const _Float16* __restrict__ wfC,
                const float* __restrict__ b2,       // [512]
                float* __restrict__ r2)             // [B, T, 128]
{
    const int blk = blockIdx.x;
    const int b0b = blk * GG;
    const int tid = threadIdx.x;
    const int w = tid >> 6, l = tid & 63;
    const int l15 = l & 15, lq = l >> 4;
    const int jb = 16 * w + 4 * lq;

    uint4 af[24];
    {
        const uint4* wf4 = reinterpret_cast<const uint4*>(wfC);
        #pragma unroll
        for (int g = 0; g < 4; ++g)
            #pragma unroll
            for (int kt = 0; kt < 6; ++kt) {
                af[g * 6 + kt] = wf4[((w * 4 + g) * 6 + kt) * 64 + l];
                pin4(af[g * 6 + kt]);
            }
    }
    unsigned bpk[8];
    #pragma unroll
    for (int g = 0; g < 4; ++g)
        #pragma unroll
        for (int p = 0; p < 2; ++p)
            bpk[g * 2 + p] = pack_f16(b2[g * 128 + jb + 2 * p],
                                      b2[g * 128 + jb + 2 * p + 1]);

    __shared__ alignas(16) uint4 H2F[2][4][64];    // h2 frags (kt2-5)

    if (tid < 256) H2F[0][tid >> 6][tid & 63] = (uint4){0, 0, 0, 0};  // h2(-1)=0

    uint4 br0, br1;                                 // r1 frag prefetch (t=0)
    {
        size_t o = ((size_t)blk * TT) * 128 + l;
        br0 = r1f[o]; br1 = r1f[o + 64];
    }
    step_barrier();

    float c[4] = {0.f, 0.f, 0.f, 0.f};

    for (int m = 0; m < TT; ++m) {
        const int cur = m & 1, nxt = cur ^ 1;

        uint4 cr0 = br0, cr1 = br1;
        if (m + 1 < TT) {
            size_t o = ((size_t)blk * TT + (m + 1)) * 128 + l;
            br0 = r1f[o]; br1 = r1f[o + 64];
        }

        f16x8 bh[4];
        #pragma unroll
        for (int kt = 0; kt < 4; ++kt)
            bh[kt] = reinterpret_cast<const f16x8*>(&H2F[cur][kt][0])[l];
        f16x8 b0v = __builtin_bit_cast(f16x8, cr0);
        f16x8 b1v = __builtin_bit_cast(f16x8, cr1);

        f32x4 accA[4], accB[4];
        #pragma unroll
        for (int g = 0; g < 4; ++g) {
            float2 u0 = unpack_f16(bpk[2 * g]);
            float2 u1 = unpack_f16(bpk[2 * g + 1]);
            accA[g] = (f32x4){u0.x, u0.y, u1.x, u1.y};
            accB[g] = (f32x4){0.f, 0.f, 0.f, 0.f};
        }
        #pragma unroll
        for (int g = 0; g < 4; ++g) {
            accA[g] = __builtin_amdgcn_mfma_f32_16x16x32_f16(
                __builtin_bit_cast(f16x8, af[g * 6 + 0]), b0v, accA[g], 0, 0, 0);
            accB[g] = __builtin_amdgcn_mfma_f32_16x16x32_f16(
                __builtin_bit_cast(f16x8, af[g * 6 + 1]), b1v, accB[g], 0, 0, 0);
            accA[g] = __builtin_amdgcn_mfma_f32_16x16x32_f16(
                __builtin_bit_cast(f16x8, af[g * 6 + 2]), bh[0], accA[g], 0, 0, 0);
            accB[g] = __builtin_amdgcn_mfma_f32_16x16x32_f16(
                __builtin_bit_cast(f16x8, af[g * 6 + 3]), bh[1], accB[g], 0, 0, 0);
            accA[g] = __builtin_amdgcn_mfma_f32_16x16x32_f16(
                __builtin_bit_cast(f16x8, af[g * 6 + 4]), bh[2], accA[g], 0, 0, 0);
            accB[g] = __builtin_amdgcn_mfma_f32_16x16x32_f16(
                __builtin_bit_cast(f16x8, af[g * 6 + 5]), bh[3], accB[g], 0, 0, 0);
        }

        float h[4];
        #pragma unroll
        for (int r = 0; r < 4; ++r) {
            float ai  = fast_sigmoid(accA[0][r] + accB[0][r]);
            float afg = fast_sigmoid(accA[1][r] + accB[1][r]);
            float ag  = fast_tanh(accA[2][r] + accB[2][r]);
            float ao  = fast_sigmoid(accA[3][r] + accB[3][r]);
            c[r] = fmaf(afg, c[r], ai * ag);
            h[r] = ao * fast_tanh(c[r]);
        }
        uint2 hp = make_uint2(pack_f16(h[0], h[1]), pack_f16(h[2], h[3]));
        *(uint2*)FRAG_PTR(H2F[nxt], jb, l15) = hp;
        float4 hv = make_float4(h[0], h[1], h[2], h[3]);
        *reinterpret_cast<float4*>(
            r2 + ((size_t)(b0b + l15) * TT + m) * 128 + jb) = hv;
        step_barrier();
    }
}

// out[bt] = tanh(dot(r2[bt,:128], Wl) + bl)
__global__ __launch_bounds__(256) void final_proj(
    const float* __restrict__ r, const float* __restrict__ Wl,
    const float* __restrict__ bl, float* __restrict__ out)
{
    __shared__ float wl[128];
    const int tid = threadIdx.x;
    if (tid < 128) wl[tid] = Wl[tid];
    __syncthreads();

    const int bt = blockIdx.x * 256 + tid;
    const float4* rr = reinterpret_cast<const float4*>(r + (size_t)bt * 128);
    float a0 = 0.f, a1 = 0.f, a2 = 0.f, a3 = 0.f;
    #pragma unroll
    for (int k = 0; k < 32; ++k) {
        float4 v = rr[k];
        a0 = fmaf(v.x, wl[4 * k + 0], a0);
        a1 = fmaf(v.y, wl[4 * k + 1], a1);
        a2 = fmaf(v.z, wl[4 * k + 2], a2);
        a3 = fmaf(v.w, wl[4 * k + 3], a3);
    }
    out[bt] = tanhf(((a0 + a1) + (a2 + a3)) + bl[0]);
}

extern "C" void kernel_launch(void* const* d_in, const int* in_sizes, int n_in,
                              void* d_out, int out_size, void* d_ws, size_t ws_size,
                              hipStream_t stream) {
    const float* input = (const float*)d_in[0];
    const float* h_0   = (const float*)d_in[1];
    const float* c_0   = (const float*)d_in[2];
    const float* Wih0  = (const float*)d_in[3];
    const float* Whh0  = (const float*)d_in[4];
    const float* b0    = (const float*)d_in[5];
    const float* Wih1  = (const float*)d_in[6];
    const float* Whh1  = (const float*)d_in[7];
    const float* b1    = (const float*)d_in[8];
    const float* Wih2  = (const float*)d_in[9];
    const float* Whh2  = (const float*)d_in[10];
    const float* b2    = (const float*)d_in[11];
    const float* Wl    = (const float*)d_in[12];
    const float* bl    = (const float*)d_in[13];

    float* out = (float*)d_out;                 // [B*T] head output
    float* r2  = out + (size_t)BB * TT;         // [B,T,128] second output

    char* ws = (char*)d_ws;
    uint4*    xf123 = (uint4*)ws;                          // 50,331,648 B
    uint2*    xf4c  = (uint2*)(ws + 50331648);             //  2,097,152 B
    uint4*    r1f   = (uint4*)(ws + 52428800);             // 33,554,432 B
    _Float16* wfA0  = (_Float16*)(ws + 85983232);          //     40,960 B
    _Float16* wfA1  = (_Float16*)(ws + 86024192);          //     49,152 B
    _Float16* wfC   = (_Float16*)(ws + 86073344);          //    196,608 B

    hipLaunchKernelGGL(reorder_wf, dim3(560), dim3(256), 0, stream,
                       Wih0, Whh0, Wih1, Whh1, Wih2, Whh2, wfA0, wfA1, wfC);
    hipLaunchKernelGGL(pack_x, dim3(13312), dim3(256), 0, stream,
                       input, xf123, xf4c);
    hipLaunchKernelGGL(lstm01_mfma, dim3(NBLK), dim3(384), 0, stream,
                       xf123, xf4c, wfA0, wfA1, b0, b1, h_0, c_0, r1f);
    hipLaunchKernelGGL(lstm2_mfma, dim3(NBLK), dim3(512), 0, stream,
                       r1f, wfC, b2, r2);
    hipLaunchKernelGGL(final_proj, dim3(BB * TT / 256), dim3(256), 0, stream,
                       r2, Wl, bl, out);
}